// Round 3
// baseline (3290.456 us; speedup 1.0000x reference)
//
#include <hip/hip_runtime.h>
#include <hip/hip_bf16.h>
#include <math.h>

typedef __bf16 bf16;
typedef float  f32x4  __attribute__((ext_vector_type(4)));
typedef float  f32x16 __attribute__((ext_vector_type(16)));
typedef bf16   bf16x8 __attribute__((ext_vector_type(8)));
typedef bf16   bf16x4 __attribute__((ext_vector_type(4)));
typedef unsigned long long u64;

#define NB 64
#define NT 256
#define NS 256
#define ND 512

__device__ __forceinline__ f32x4 mfma16(bf16x8 a, bf16x8 b, f32x4 c) {
  return __builtin_amdgcn_mfma_f32_16x16x32_bf16(a, b, c, 0, 0, 0);
}
__device__ __forceinline__ f32x16 mfma32(bf16x8 a, bf16x8 b, f32x16 c) {
  return __builtin_amdgcn_mfma_f32_32x32x16_bf16(a, b, c, 0, 0, 0);
}

// ---------------- weight cast / transpose to [N][K] bf16 ----------------
// lo=0: v = src ; lo=1: v = src - bf16(src)  (residual for split-bf16 GEMM)
__global__ void k_cast_bt(bf16* dst, int dstStride, int N, int K,
                          const float* src, int srcLd, int srcOff, int transpose,
                          int lo) {
  int id = blockIdx.x * 256 + threadIdx.x;
  if (id >= N * K) return;
  int n = id / K, k = id % K;
  float v = transpose ? src[(size_t)k * srcLd + srcOff + n]
                      : src[(size_t)n * srcLd + srcOff + k];
  if (lo) v = v - (float)(bf16)v;
  dst[(size_t)n * dstStride + k] = (bf16)v;
}

// xlo = bf16(x - xhi)  (vector4)
__global__ void k_lo(const float* __restrict__ x, const bf16* __restrict__ xhi,
                     bf16* __restrict__ xlo, int n4) {
  int id = blockIdx.x * 256 + threadIdx.x;
  if (id >= n4) return;
  float4 v = ((const float4*)x)[id];
  bf16x4 h = ((const bf16x4*)xhi)[id];
  bf16x4 o;
  o[0] = (bf16)(v.x - (float)h[0]); o[1] = (bf16)(v.y - (float)h[1]);
  o[2] = (bf16)(v.z - (float)h[2]); o[3] = (bf16)(v.w - (float)h[3]);
  ((bf16x4*)xlo)[id] = o;
}

__global__ void k_init(const float* h0, bf16* h0bf, unsigned* bar) {
  int id = blockIdx.x * 256 + threadIdx.x;
  if (id < NB * ND) h0bf[id] = (bf16)h0[id];
  if (id < 1024) bar[id] = 0u;
}

// ---------------- embedding gather -> Abuf bf16 [16384][1536] ----------------
__global__ void k_embed(const int* __restrict__ nt, const int* __restrict__ pr,
                        const int* __restrict__ par, const float* __restrict__ nt_emb,
                        const float* __restrict__ rule_emb, bf16* __restrict__ Abuf) {
  int r = blockIdx.x;
  int tid = threadIdx.x;         // 128 threads
  const float* s0 = nt_emb  + (size_t)nt[r]  * 512;
  const float* s1 = rule_emb + (size_t)pr[r]  * 512;
  const float* s2 = rule_emb + (size_t)par[r] * 512;
  bf16* drow = Abuf + (size_t)r * 1536;
  for (int v = 0; v < 3; ++v) {
    int col = (tid + v * 128) * 4;
    const float* s = (col < 512) ? (s0 + col) : (col < 1024 ? s1 + col - 512 : s2 + col - 1024);
    float4 x = *(const float4*)s;
    bf16x4 y; y[0] = (bf16)x.x; y[1] = (bf16)x.y; y[2] = (bf16)x.z; y[3] = (bf16)x.w;
    *(bf16x4*)(drow + col) = y;
  }
}

// ---------------- generic bf16 MFMA GEMM: C[M,N] = concat(A0,A1,A2) @ Bt^T ----------------
__global__ __launch_bounds__(256) void k_gemm(
    const bf16* __restrict__ A0, int k0, const bf16* __restrict__ A1, int k1,
    const bf16* __restrict__ A2, int k2, const bf16* __restrict__ Bt,
    int Ktot, int N, int nbx, const float* __restrict__ bias, int act,
    float* __restrict__ Cf, bf16* __restrict__ Cbf) {
  __shared__ bf16 Al[128 * 40];
  __shared__ bf16 Bl[128 * 40];
  const int tid = threadIdx.x;
  const int bx = blockIdx.x % nbx, by = blockIdx.x / nbx;
  const int w = tid >> 6, l = tid & 63;
  const int wm = (w & 1) * 64, wn = (w >> 1) * 64;
  const int la = l & 15, kq = (l >> 4) * 8;
  const int srow = tid >> 1, skh = (tid & 1) * 16;
  const int m_g = by * 128 + srow;
  const bf16* brow = Bt + (size_t)(bx * 128 + srow) * Ktot;

  f32x4 acc[4][4];
  f32x4 z; z[0] = 0.f; z[1] = 0.f; z[2] = 0.f; z[3] = 0.f;
#pragma unroll
  for (int mt = 0; mt < 4; ++mt)
#pragma unroll
    for (int nt2 = 0; nt2 < 4; ++nt2) acc[mt][nt2] = z;

  for (int kt = 0; kt < Ktot; kt += 32) {
    __syncthreads();
    {
      int kg = kt + skh;
      const bf16* p;
      int kk = kg;
      if (kk < k0) p = A0 + (size_t)m_g * k0 + kk;
      else { kk -= k0;
        if (kk < k1) p = A1 + (size_t)m_g * k1 + kk;
        else { kk -= k1; p = A2 + (size_t)m_g * k2 + kk; } }
      *(bf16x8*)(&Al[srow * 40 + skh])     = *(const bf16x8*)p;
      *(bf16x8*)(&Al[srow * 40 + skh + 8]) = *(const bf16x8*)(p + 8);
      const bf16* q = brow + kt + skh;
      *(bf16x8*)(&Bl[srow * 40 + skh])     = *(const bf16x8*)q;
      *(bf16x8*)(&Bl[srow * 40 + skh + 8]) = *(const bf16x8*)(q + 8);
    }
    __syncthreads();
    bf16x8 af[4], bfr[4];
#pragma unroll
    for (int mt = 0; mt < 4; ++mt) af[mt]  = *(const bf16x8*)(&Al[(wm + mt * 16 + la) * 40 + kq]);
#pragma unroll
    for (int nt2 = 0; nt2 < 4; ++nt2) bfr[nt2] = *(const bf16x8*)(&Bl[(wn + nt2 * 16 + la) * 40 + kq]);
#pragma unroll
    for (int mt = 0; mt < 4; ++mt)
#pragma unroll
      for (int nt2 = 0; nt2 < 4; ++nt2)
        acc[mt][nt2] = mfma16(af[mt], bfr[nt2], acc[mt][nt2]);
  }
  const int r4 = (l >> 4) * 4, cc = l & 15;
#pragma unroll
  for (int mt = 0; mt < 4; ++mt)
#pragma unroll
    for (int nt2 = 0; nt2 < 4; ++nt2)
#pragma unroll
      for (int i = 0; i < 4; ++i) {
        int mm = by * 128 + wm + mt * 16 + r4 + i;
        int nn = bx * 128 + wn + nt2 * 16 + cc;
        float v = acc[mt][nt2][i];
        if (bias) v += bias[nn];
        if (act) v = tanhf(v);
        size_t off = (size_t)mm * N + nn;
        if (Cf)  Cf[off]  = v;
        if (Cbf) Cbf[off] = (bf16)v;
      }
}

// ---------------- persistent LSTM chain v5 ----------------
// 64 blocks x 512 threads. Block = (bg: batch-half, 32 rows) x (cg: d-slice 16 =>
// 64 gate cols). Waves w = n2 + 2*kq. kq 0,1: h.Whh K-half, A-frags loaded DIRECTLY
// from Ht into registers (no LDS staging, no S_d). kq 2,3: parent half, A-frags
// register-prefetched a step ahead from Hbf; late (pv==t) lanes load from Ht at the
// next MFMA phase (wave polls only then). Per-wave polling: each wave polls ONLY the
// 16 producers of its K-range (1 flag/lane, 4x redundant). Release: per-wave
// vmcnt(0) then lane0 fetch_add(+1) on the block flag (target 4(t+1)); no LDS
// counter. gls double-buffered by step parity => ONE __syncthreads per step.
#define LSTM_LDS 69632

__global__ __launch_bounds__(512, 2) void k_lstm_all(
    const bf16* __restrict__ gpre, const bf16* __restrict__ W2bt,
    const int* __restrict__ parent_idx, const bf16* __restrict__ h0bf,
    const float* __restrict__ c0,
    bf16* __restrict__ Hbf,      // batch-major [B*T][512] (parents + downstream)
    bf16* __restrict__ Ht,       // time-major  [T*B][512] (coalesced h broadcast)
    float* __restrict__ H, unsigned* __restrict__ flags) {
  extern __shared__ char smem[];
  float* gls = (float*)smem;     // [2 parity][4 quarters][32 rows][68]

  const int tid = threadIdx.x;
  const int bid = blockIdx.x;
  const int bg = (bid >> 2) & 1;
  const int cg = (bid & 3) | ((bid >> 3) << 2);
  const int d0 = cg * 16;
  const int w = tid >> 6, l = tid & 63;
  const int la32 = l & 31, lhi = l >> 5, kq8 = lhi * 8;
  const int n2 = w & 1, kq = w >> 1;           // kq = K-quarter 0..3
  const int lc = n2 * 32 + la32;               // local gate col 0..63
  const int ng = (lc >> 4) * 512 + d0 + (lc & 15);  // global gate row in W2bt
  const int row = bg * 32 + la32;              // batch row (MFMA A row)

  // producers of this wave's K-range: cg_p = (kq&1)*16 + (l&15)
  const int cgp = (kq & 1) * 16 + (l & 15);
  const int bidp = (cgp & 3) | (bg << 2) | ((cgp >> 2) << 3);
  const unsigned* fptr = flags + bidp * 16;

  // ---- weights: 16 K-chunks of this lane's (gate-col, K-quarter), in VGPRs ----
  bf16x8 wf[16];
#pragma unroll
  for (int kc = 0; kc < 16; ++kc)
    wf[kc] = *(const bf16x8*)(W2bt + (size_t)ng * 1024 + kq * 256 + kc * 16 + kq8);

  // ---- pointwise mapping (tid < 256): cells (bg*32+pb, d0+pdh .. +1) ----
  const int pb = (tid & 255) >> 3, pdh = (tid & 7) * 2;
  const int gb = bg * 32 + pb;
  float creg0 = 0.f, creg1 = 0.f;
  unsigned g_pf[4];
  if (tid < 256) {
    creg0 = c0[(size_t)gb * ND + d0 + pdh];
    creg1 = c0[(size_t)gb * ND + d0 + pdh + 1];
#pragma unroll
    for (int g = 0; g < 4; ++g)
      g_pf[g] = *(const unsigned*)(gpre + ((size_t)gb * NT) * 2048 + g * 512 + d0 + pdh);
  }

  // ---- parent A-frags (registers) ----
  union frag { u64 q[2]; bf16x8 v; };
  frag af[16];
#pragma unroll
  for (int kc = 0; kc < 16; ++kc) { af[kc].q[0] = 0ull; af[kc].q[1] = 0ull; }
  bool latereg = false;

  f32x16 acc;
#pragma unroll
  for (int i = 0; i < 16; ++i) acc[i] = 0.f;

  for (int t = 0; t < NT; ++t) {
    float* gp = gls + (t & 1) * 8704;
    const unsigned tgt = 4u * (unsigned)t;

    if (w < 4) {
      // ---- h-half: poll own 16 producers, then A-frags direct to registers ----
      if (t > 0) {
        while (true) {
          unsigned v = __hip_atomic_load(fptr, __ATOMIC_RELAXED, __HIP_MEMORY_SCOPE_AGENT);
          if (__all((int)(v >= tgt))) break;
          __builtin_amdgcn_s_sleep(1);
        }
        __builtin_amdgcn_sched_barrier(0);
      }
      const bf16* hbase = (t == 0) ? (h0bf + (size_t)(bg * 32) * ND)
                                   : (Ht + ((size_t)(t - 1) * NB + bg * 32) * ND);
      const bf16* hp = hbase + (size_t)la32 * ND + kq * 256 + kq8;
      frag hf[16];
#pragma unroll
      for (int kc = 0; kc < 16; ++kc) {
        hf[kc].q[0] = __hip_atomic_load((const u64*)(hp + kc * 16),
                                        __ATOMIC_RELAXED, __HIP_MEMORY_SCOPE_AGENT);
        hf[kc].q[1] = __hip_atomic_load((const u64*)(hp + kc * 16 + 4),
                                        __ATOMIC_RELAXED, __HIP_MEMORY_SCOPE_AGENT);
      }
#pragma unroll
      for (int kc = 0; kc < 16; ++kc) acc = mfma32(hf[kc].v, wf[kc], acc);
    } else {
      // ---- parent half: register-prefetched; late lanes fetch h(t-1) now ----
      if (__ballot(latereg)) {
        while (true) {
          unsigned v = __hip_atomic_load(fptr, __ATOMIC_RELAXED, __HIP_MEMORY_SCOPE_AGENT);
          if (__all((int)(v >= tgt))) break;
          __builtin_amdgcn_s_sleep(1);
        }
        __builtin_amdgcn_sched_barrier(0);
        if (latereg) {
          const bf16* pp = Ht + ((size_t)(t - 1) * NB + row) * ND + (kq - 2) * 256 + kq8;
#pragma unroll
          for (int kc = 0; kc < 16; ++kc) {
            af[kc].q[0] = __hip_atomic_load((const u64*)(pp + kc * 16),
                                            __ATOMIC_RELAXED, __HIP_MEMORY_SCOPE_AGENT);
            af[kc].q[1] = __hip_atomic_load((const u64*)(pp + kc * 16 + 4),
                                            __ATOMIC_RELAXED, __HIP_MEMORY_SCOPE_AGENT);
          }
        }
      }
#pragma unroll
      for (int kc = 0; kc < 16; ++kc) acc = mfma32(af[kc].v, wf[kc], acc);
    }

    // ---- K-quarter partials -> gls (parity buffer) ----
#pragma unroll
    for (int i = 0; i < 16; ++i) {
      int r = (i & 3) + 8 * (i >> 2) + 4 * lhi;   // verified 32x32 C/D mapping
      gp[(kq * 32 + r) * 68 + lc] = acc[i];
    }
#pragma unroll
    for (int i = 0; i < 16; ++i) acc[i] = 0.f;
    __syncthreads();  // S_a (only barrier per step)

    if (tid < 256) {
      // ---- pointwise: sum 4 quarters + gpre, gates, cell update ----
      union { unsigned u; bf16 h[2]; } gv[4];
#pragma unroll
      for (int g = 0; g < 4; ++g) gv[g].u = g_pf[g];
      float hn[2];
#pragma unroll
      for (int j = 0; j < 2; ++j) {
        float s[4];
#pragma unroll
        for (int g = 0; g < 4; ++g) {
          float v = 0.f;
#pragma unroll
          for (int q = 0; q < 4; ++q) v += gp[(q * 32 + pb) * 68 + g * 16 + pdh + j];
          s[g] = v + (float)gv[g].h[j];
        }
        float si = 1.f / (1.f + __expf(-s[0]));
        float sf = 1.f / (1.f + __expf(-s[1]));
        float so = 1.f / (1.f + __expf(-s[3]));
        float e2 = __expf(2.f * fminf(fmaxf(s[2], -15.f), 15.f));
        float tg = (e2 - 1.f) / (e2 + 1.f);
        float cp = j ? creg1 : creg0;
        float cn = sf * cp + si * tg;
        float e2c = __expf(2.f * fminf(fmaxf(cn, -15.f), 15.f));
        float tc = (e2c - 1.f) / (e2c + 1.f);
        if (j) creg1 = cn; else creg0 = cn;
        hn[j] = so * tc;
      }
      union { unsigned u; bf16 h[2]; } pk;
      pk.h[0] = (bf16)hn[0]; pk.h[1] = (bf16)hn[1];
      size_t hb = ((size_t)gb * NT + t) * ND + d0 + pdh;
      size_t ho = ((size_t)t * NB + gb) * ND + d0 + pdh;
      __hip_atomic_store((unsigned*)(Hbf + hb), pk.u, __ATOMIC_RELAXED, __HIP_MEMORY_SCOPE_AGENT);
      __hip_atomic_store((unsigned*)(Ht + ho), pk.u, __ATOMIC_RELAXED, __HIP_MEMORY_SCOPE_AGENT);
      if (t + 1 < NT) {
        // release: drain this wave's 2 stores, one atomic add on the block flag
        asm volatile("s_waitcnt vmcnt(0)" ::: "memory");
        if (l == 0)
          __hip_atomic_fetch_add(flags + bid * 16, 1u,
                                 __ATOMIC_RELAXED, __HIP_MEMORY_SCOPE_AGENT);
      }
      *(float2*)(H + hb) = make_float2(hn[0], hn[1]);   // off release path
      if (t + 1 < NT) {
#pragma unroll
        for (int g = 0; g < 4; ++g)
          g_pf[g] = *(const unsigned*)(gpre + ((size_t)gb * NT + (t + 1)) * 2048 + g * 512 + d0 + pdh);
      }
    } else if (t + 1 < NT) {
      // ---- parent prefetch (waves 4-7): A-frags for step t+1 into registers ----
      int pv = parent_idx[(size_t)row * NT + (t + 1)];
      latereg = (pv == t);
      if (pv < t) {                      // visible history: prefetch now
        const bf16* psrc = Hbf + ((size_t)row * NT + pv) * ND + (kq - 2) * 256;
#pragma unroll
        for (int kc = 0; kc < 16; ++kc) {
          af[kc].q[0] = __hip_atomic_load((const u64*)(psrc + kc * 16 + kq8),
                                          __ATOMIC_RELAXED, __HIP_MEMORY_SCOPE_AGENT);
          af[kc].q[1] = __hip_atomic_load((const u64*)(psrc + kc * 16 + kq8 + 4),
                                          __ATOMIC_RELAXED, __HIP_MEMORY_SCOPE_AGENT);
        }
      } else if (!latereg) {             // future parent -> zeros
#pragma unroll
        for (int kc = 0; kc < 16; ++kc) { af[kc].q[0] = 0ull; af[kc].q[1] = 0ull; }
      }
    }
  }
}

// ---------------- fused attention: scores (fp32) + softmax + context ----------------
__global__ __launch_bounds__(256) void k_attn(
    const float* __restrict__ Q, const float* __restrict__ ctx, bf16* __restrict__ Cbf,
    float* __restrict__ prob0, float* __restrict__ prob1) {
  __shared__ float Sl[64 * 257];
  __shared__ float T1[16 * 68];
  __shared__ float T2[16 * 68];
  const int tid = threadIdx.x;
  const int b = blockIdx.x >> 2, ch = blockIdx.x & 3;
  const int t0 = ch * 64;
  const int row0 = b * NT + t0;
  const int ty = tid >> 4, tx = tid & 15;
  const int sl_r = tid >> 2, sl_k = (tid & 3) * 4;

  for (int sc = 0; sc < 4; ++sc) {
    float acc[4][4] = {};
    for (int kc = 0; kc < 512; kc += 16) {
      __syncthreads();
      float4 q4 = *(const float4*)(Q + (size_t)(row0 + sl_r) * ND + kc + sl_k);
      T1[(sl_k + 0) * 68 + sl_r] = q4.x; T1[(sl_k + 1) * 68 + sl_r] = q4.y;
      T1[(sl_k + 2) * 68 + sl_r] = q4.z; T1[(sl_k + 3) * 68 + sl_r] = q4.w;
      float4 c4 = *(const float4*)(ctx + (size_t)(b * NS + sc * 64 + sl_r) * ND + kc + sl_k);
      T2[(sl_k + 0) * 68 + sl_r] = c4.x; T2[(sl_k + 1) * 68 + sl_r] = c4.y;
      T2[(sl_k + 2) * 68 + sl_r] = c4.z; T2[(sl_k + 3) * 68 + sl_r] = c4.w;
      __syncthreads();
#pragma unroll
      for (int kk = 0; kk < 16; ++kk) {
        float4 qv = *(const float4*)(&T1[kk * 68 + ty * 4]);
        float4 cv = *(const float4*)(&T2[kk * 68 + tx * 4]);
        float qa[4] = {qv.x, qv.y, qv.z, qv.w};
        float ca[4] = {cv.x, cv.y, cv.z, cv.w};
#pragma unroll
        for (int i = 0; i < 4; ++i)
#pragma unroll
          for (int j = 0; j < 4; ++j) acc[i][j] += qa[i] * ca[j];
      }
    }
#pragma unroll
    for (int i = 0; i < 4; ++i)
#pragma unroll
      for (int j = 0; j < 4; ++j)
        Sl[(ty * 4 + i) * 257 + sc * 64 + tx * 4 + j] = acc[i][j];
  }
  __syncthreads();

  if (tid < 64) {
    float* row = &Sl[tid * 257];
    float mx = -1e30f;
    for (int s = 0; s < 256; ++s) mx = fmaxf(mx, row[s]);
    float sum = 0.f;
    for (int s = 0; s < 256; ++s) { float e = __expf(row[s] - mx); row[s] = e; sum += e; }
    float inv = 1.f / sum;
    for (int s = 0; s < 256; ++s) row[s] *= inv;
  }
  __syncthreads();
  if (prob0) {
    int pr = tid >> 2, pq = (tid & 3) * 64;
    size_t po = (size_t)(row0 + pr) * NS + pq;
    for (int s = 0; s < 64; s += 4) {
      float4 o; o.x = Sl[pr * 257 + pq + s];     o.y = Sl[pr * 257 + pq + s + 1];
      o.z = Sl[pr * 257 + pq + s + 2];           o.w = Sl[pr * 257 + pq + s + 3];
      *(float4*)(prob0 + po + s) = o;
      *(float4*)(prob1 + po + s) = o;
    }
  }

  const int c_sr = tid >> 4, c_n4 = (tid & 15) * 4;
  for (int dc = 0; dc < 512; dc += 64) {
    float acc[4][4] = {};
    for (int s0c = 0; s0c < 256; s0c += 16) {
      __syncthreads();
      *(float4*)(&T2[c_sr * 68 + c_n4]) =
          *(const float4*)(ctx + (size_t)(b * NS + s0c + c_sr) * ND + dc + c_n4);
      __syncthreads();
#pragma unroll
      for (int kk = 0; kk < 16; ++kk) {
        float p0 = Sl[(ty * 4 + 0) * 257 + s0c + kk];
        float p1 = Sl[(ty * 4 + 1) * 257 + s0c + kk];
        float p2 = Sl[(ty * 4 + 2) * 257 + s0c + kk];
        float p3 = Sl[(ty * 4 + 3) * 257 + s0c + kk];
        float4 cv = *(const float4*)(&T2[kk * 68 + tx * 4]);
        float ca[4] = {cv.x, cv.y, cv.z, cv.w};
#pragma unroll
        for (int j = 0; j < 4; ++j) {
          acc[0][j] += p0 * ca[j]; acc[1][j] += p1 * ca[j];
          acc[2][j] += p2 * ca[j]; acc[3][j] += p3 * ca[j];
        }
      }
    }
#pragma unroll
    for (int i = 0; i < 4; ++i)
#pragma unroll
      for (int j = 0; j < 4; ++j)
        Cbf[(size_t)(row0 + ty * 4 + i) * ND + dc + tx * 4 + j] = (bf16)acc[i][j];
  }
}

// ---------------- host ----------------
extern "C" void kernel_launch(void* const* d_in, const int* in_sizes, int n_in,
                              void* d_out, int out_size, void* d_ws, size_t ws_size,
                              hipStream_t stream) {
  const int*   nt       = (const int*)d_in[0];
  const int*   prules   = (const int*)d_in[1];
  const int*   parules  = (const int*)d_in[2];
  const int*   pidx     = (const int*)d_in[3];
  const float* src_ctx  = (const float*)d_in[4];
  const float* rest_ctx = (const float*)d_in[5];
  const float* h0       = (const float*)d_in[8];
  const float* c0       = (const float*)d_in[9];
  const float* nt_emb   = (const float*)d_in[10];
  const float* rule_emb = (const float*)d_in[11];
  const float* Wih      = (const float*)d_in[12];
  const float* Whh      = (const float*)d_in[13];
  const float* b_lstm   = (const float*)d_in[14];
  const float* Wa_src   = (const float*)d_in[15];
  const float* Wo_src   = (const float*)d_in[16];
  const float* Wa_var   = (const float*)d_in[17];
  const float* Wo_var   = (const float*)d_in[18];
  const float* Wl       = (const float*)d_in[19];
  const float* bl       = (const float*)d_in[20];
  float* out = (float*)d_out;

  char* p = (char*)d_ws;
  bf16*  Abuf    = (bf16*)p;  p += 50331648;   // [16384][1536]
  bf16*  gpre    = (bf16*)p;  p += 67108864;   // [16384][2048]
  float* H       = (float*)p; p += 33554432;   // [16384][512]
  bf16*  Hbf     = (bf16*)p;  p += 16777216;
  float* SRCOUT  = (float*)p; p += 33554432;
  bf16*  SRCOUTb = (bf16*)p;  p += 16777216;
  bf16*  Wemb_bt = (bf16*)p;  p += 6291456;    // [2048][1536]
  bf16*  W2bt    = (bf16*)p;  p += 4194304;    // [2048][1024] = [Whh | Wih_par]
  bf16*  Wos_bt  = (bf16*)p;  p += 1048576;
  bf16*  Wov_bt  = (bf16*)p;  p += 1048576;
  bf16*  Wl_bt   = (bf16*)p;  p += 1572864;
  bf16*  h0bf    = (bf16*)p;  p += 65536;
  unsigned* bar  = (unsigned*)p; p += 4096;    // 64 flags, 64B-padded
  // Ht (time-major h mirror, LSTM-internal) aliases Abuf: Abuf is dead after the
  // gpre GEMM; all LSTM-side Ht accesses are agent-scope atomics (L2-bypassing), so
  // stale Abuf L2 lines are never observed. Q1 (same region) written after LSTM.
  bf16*  Ht    = (bf16*)Abuf;                  // [256*64][512] = 16 MB
  float* Q1    = (float*)Abuf;
  bf16*  C1bf  = (bf16*)((char*)Abuf + 33554432);
  float* Q2    = (float*)gpre;
  bf16*  C2bf  = (bf16*)((char*)gpre + 33554432);
  bf16*  VARbf = (bf16*)((char*)gpre + 50331648);
  // split-bf16 projection temporaries (aliases of dead regions):
  bf16*  Hlo   = (bf16*)((char*)gpre + 16777216);  // dead before Q2 write
  bf16*  SOlo  = (bf16*)Abuf;                      // Q1 dead after src-attn
  bf16*  Was3  = Wemb_bt;                          // [512][1536] = [Whi|Wlo|Whi]
  bf16*  Wav3  = Wemb_bt + 786432;                 // (Wemb_bt dead after gpre GEMM)
  float* out_p0 = out + 8388608;
  float* out_p1 = out + 12582912;

  hipFuncSetAttribute(reinterpret_cast<const void*>(k_lstm_all),
                      hipFuncAttributeMaxDynamicSharedMemorySize, LSTM_LDS);

  k_cast_bt<<<(2048*1536+255)/256, 256, 0, stream>>>(Wemb_bt, 1536, 2048, 1536, Wih, 2048, 0, 0, 0);
  k_cast_bt<<<(2048*512 +255)/256, 256, 0, stream>>>(W2bt,        1024, 2048, 512, Whh, 512, 0, 0, 0);
  k_cast_bt<<<(2048*512 +255)/256, 256, 0, stream>>>(W2bt + 512,  1024, 2048, 512, Wih, 2048, 1536, 0, 0);
  k_cast_bt<<<(512*1024 +255)/256, 256, 0, stream>>>(Wos_bt, 1024, 512, 1024, Wo_src, 512, 0, 1, 0);
  k_cast_bt<<<(512*1024 +255)/256, 256, 0, stream>>>(Wov_bt, 1024, 512, 1024, Wo_var, 512, 0, 1, 0);
  k_cast_bt<<<(512*1536 +255)/256, 256, 0, stream>>>(Wl_bt,  1536, 512, 1536, Wl, 512, 0, 1, 0);
  k_init<<<128, 256, 0, stream>>>(h0, h0bf, bar);
  k_embed<<<16384, 128, 0, stream>>>(nt, prules, parules, nt_emb, rule_emb, Abuf);

  k_gemm<<<2048, 256, 0, stream>>>(Abuf, 1536, nullptr, 0, nullptr, 0,
                                   Wemb_bt, 1536, 2048, 16, b_lstm, 0, nullptr, gpre);

  // Wemb_bt now dead -> build split-bf16 Wa panels into it
  k_cast_bt<<<(512*512+255)/256, 256, 0, stream>>>(Was3 + 0,    1536, 512, 512, Wa_src, 512, 0, 1, 0);
  k_cast_bt<<<(512*512+255)/256, 256, 0, stream>>>(Was3 + 512,  1536, 512, 512, Wa_src, 512, 0, 1, 1);
  k_cast_bt<<<(512*512+255)/256, 256, 0, stream>>>(Was3 + 1024, 1536, 512, 512, Wa_src, 512, 0, 1, 0);
  k_cast_bt<<<(512*512+255)/256, 256, 0, stream>>>(Wav3 + 0,    1536, 512, 512, Wa_var, 512, 0, 1, 0);
  k_cast_bt<<<(512*512+255)/256, 256, 0, stream>>>(Wav3 + 512,  1536, 512, 512, Wa_var, 512, 0, 1, 1);
  k_cast_bt<<<(512*512+255)/256, 256, 0, stream>>>(Wav3 + 1024, 1536, 512, 512, Wa_var, 512, 0, 1, 0);

  k_lstm_all<<<64, 512, LSTM_LDS, stream>>>(gpre, W2bt, pidx, h0bf, c0, Hbf, Ht, H, bar);

  // Q1 = H @ Wa_src in split-bf16: Hbf@Whi + Hbf@Wlo + Hlo@Whi  (fp32-accurate)
  k_lo<<<16384*512/4/256, 256, 0, stream>>>(H, Hbf, Hlo, 16384*512/4);
  k_gemm<<<512, 256, 0, stream>>>(Hbf, 512, Hbf, 512, Hlo, 512,
                                  Was3, 1536, 512, 4, nullptr, 0, Q1, nullptr);
  k_attn<<<256, 256, 0, stream>>>(Q1, src_ctx, C1bf, nullptr, nullptr);
  k_gemm<<<512, 256, 0, stream>>>(C1bf, 512, Hbf, 512, nullptr, 0,
                                  Wos_bt, 1024, 512, 4, nullptr, 1, SRCOUT, SRCOUTb);
  // Q2 = SRCOUT @ Wa_var in split-bf16
  k_lo<<<16384*512/4/256, 256, 0, stream>>>(SRCOUT, SRCOUTb, SOlo, 16384*512/4);
  k_gemm<<<512, 256, 0, stream>>>(SRCOUTb, 512, SRCOUTb, 512, SOlo, 512,
                                  Wav3, 1536, 512, 4, nullptr, 0, Q2, nullptr);
  k_attn<<<256, 256, 0, stream>>>(Q2, rest_ctx, C2bf, out_p0, out_p1);
  k_gemm<<<512, 256, 0, stream>>>(C2bf, 512, SRCOUTb, 512, nullptr, 0,
                                  Wov_bt, 1024, 512, 4, nullptr, 1, nullptr, VARbf);
  k_gemm<<<512, 256, 0, stream>>>(Hbf, 512, SRCOUTb, 512, VARbf, 512,
                                  Wl_bt, 1536, 512, 4, bl, 1, out, nullptr);
}

// Round 4
// 2878.118 us; speedup vs baseline: 1.1433x; 1.1433x over previous
//
#include <hip/hip_runtime.h>
#include <hip/hip_bf16.h>
#include <math.h>

typedef __bf16 bf16;
typedef float  f32x4  __attribute__((ext_vector_type(4)));
typedef float  f32x16 __attribute__((ext_vector_type(16)));
typedef bf16   bf16x8 __attribute__((ext_vector_type(8)));
typedef bf16   bf16x4 __attribute__((ext_vector_type(4)));
typedef unsigned long long u64;

#define NB 64
#define NT 256
#define NS 256
#define ND 512

__device__ __forceinline__ f32x4 mfma16(bf16x8 a, bf16x8 b, f32x4 c) {
  return __builtin_amdgcn_mfma_f32_16x16x32_bf16(a, b, c, 0, 0, 0);
}
__device__ __forceinline__ f32x16 mfma32(bf16x8 a, bf16x8 b, f32x16 c) {
  return __builtin_amdgcn_mfma_f32_32x32x16_bf16(a, b, c, 0, 0, 0);
}

// bf16-NaN sentinel pair (per-u32 check; each u32 is one atomic producer store)
#define SENT 0x7FC07FC0u
__device__ __forceinline__ bool badq(u64 x) {
  return ((unsigned)x == SENT) || ((unsigned)(x >> 32) == SENT);
}

// ---------------- weight cast / transpose to [N][K] bf16 ----------------
// lo=0: v = src ; lo=1: v = src - bf16(src)  (residual for split-bf16 GEMM)
__global__ void k_cast_bt(bf16* dst, int dstStride, int N, int K,
                          const float* src, int srcLd, int srcOff, int transpose,
                          int lo) {
  int id = blockIdx.x * 256 + threadIdx.x;
  if (id >= N * K) return;
  int n = id / K, k = id % K;
  float v = transpose ? src[(size_t)k * srcLd + srcOff + n]
                      : src[(size_t)n * srcLd + srcOff + k];
  if (lo) v = v - (float)(bf16)v;
  dst[(size_t)n * dstStride + k] = (bf16)v;
}

// xlo = bf16(x - xhi)  (vector4)
__global__ void k_lo(const float* __restrict__ x, const bf16* __restrict__ xhi,
                     bf16* __restrict__ xlo, int n4) {
  int id = blockIdx.x * 256 + threadIdx.x;
  if (id >= n4) return;
  float4 v = ((const float4*)x)[id];
  bf16x4 h = ((const bf16x4*)xhi)[id];
  bf16x4 o;
  o[0] = (bf16)(v.x - (float)h[0]); o[1] = (bf16)(v.y - (float)h[1]);
  o[2] = (bf16)(v.z - (float)h[2]); o[3] = (bf16)(v.w - (float)h[3]);
  ((bf16x4*)xlo)[id] = o;
}

__global__ void k_init(const float* h0, bf16* h0bf, unsigned* hx) {
  int id = blockIdx.x * 256 + threadIdx.x;
  if (id < NB * ND) h0bf[id] = (bf16)h0[id];
#pragma unroll
  for (int k = 0; k < 2; ++k) hx[id + k * 32768] = SENT;   // 256 KB sentinel fill
}

// ---------------- embedding gather -> Abuf bf16 [16384][1536] ----------------
__global__ void k_embed(const int* __restrict__ nt, const int* __restrict__ pr,
                        const int* __restrict__ par, const float* __restrict__ nt_emb,
                        const float* __restrict__ rule_emb, bf16* __restrict__ Abuf) {
  int r = blockIdx.x;
  int tid = threadIdx.x;         // 128 threads
  const float* s0 = nt_emb  + (size_t)nt[r]  * 512;
  const float* s1 = rule_emb + (size_t)pr[r]  * 512;
  const float* s2 = rule_emb + (size_t)par[r] * 512;
  bf16* drow = Abuf + (size_t)r * 1536;
  for (int v = 0; v < 3; ++v) {
    int col = (tid + v * 128) * 4;
    const float* s = (col < 512) ? (s0 + col) : (col < 1024 ? s1 + col - 512 : s2 + col - 1024);
    float4 x = *(const float4*)s;
    bf16x4 y; y[0] = (bf16)x.x; y[1] = (bf16)x.y; y[2] = (bf16)x.z; y[3] = (bf16)x.w;
    *(bf16x4*)(drow + col) = y;
  }
}

// ---------------- generic bf16 MFMA GEMM: C[M,N] = concat(A0,A1,A2) @ Bt^T ----------------
__global__ __launch_bounds__(256) void k_gemm(
    const bf16* __restrict__ A0, int k0, const bf16* __restrict__ A1, int k1,
    const bf16* __restrict__ A2, int k2, const bf16* __restrict__ Bt,
    int Ktot, int N, int nbx, const float* __restrict__ bias, int act,
    float* __restrict__ Cf, bf16* __restrict__ Cbf) {
  __shared__ bf16 Al[128 * 40];
  __shared__ bf16 Bl[128 * 40];
  const int tid = threadIdx.x;
  const int bx = blockIdx.x % nbx, by = blockIdx.x / nbx;
  const int w = tid >> 6, l = tid & 63;
  const int wm = (w & 1) * 64, wn = (w >> 1) * 64;
  const int la = l & 15, kq = (l >> 4) * 8;
  const int srow = tid >> 1, skh = (tid & 1) * 16;
  const int m_g = by * 128 + srow;
  const bf16* brow = Bt + (size_t)(bx * 128 + srow) * Ktot;

  f32x4 acc[4][4];
  f32x4 z; z[0] = 0.f; z[1] = 0.f; z[2] = 0.f; z[3] = 0.f;
#pragma unroll
  for (int mt = 0; mt < 4; ++mt)
#pragma unroll
    for (int nt2 = 0; nt2 < 4; ++nt2) acc[mt][nt2] = z;

  for (int kt = 0; kt < Ktot; kt += 32) {
    __syncthreads();
    {
      int kg = kt + skh;
      const bf16* p;
      int kk = kg;
      if (kk < k0) p = A0 + (size_t)m_g * k0 + kk;
      else { kk -= k0;
        if (kk < k1) p = A1 + (size_t)m_g * k1 + kk;
        else { kk -= k1; p = A2 + (size_t)m_g * k2 + kk; } }
      *(bf16x8*)(&Al[srow * 40 + skh])     = *(const bf16x8*)p;
      *(bf16x8*)(&Al[srow * 40 + skh + 8]) = *(const bf16x8*)(p + 8);
      const bf16* q = brow + kt + skh;
      *(bf16x8*)(&Bl[srow * 40 + skh])     = *(const bf16x8*)q;
      *(bf16x8*)(&Bl[srow * 40 + skh + 8]) = *(const bf16x8*)(q + 8);
    }
    __syncthreads();
    bf16x8 af[4], bfr[4];
#pragma unroll
    for (int mt = 0; mt < 4; ++mt) af[mt]  = *(const bf16x8*)(&Al[(wm + mt * 16 + la) * 40 + kq]);
#pragma unroll
    for (int nt2 = 0; nt2 < 4; ++nt2) bfr[nt2] = *(const bf16x8*)(&Bl[(wn + nt2 * 16 + la) * 40 + kq]);
#pragma unroll
    for (int mt = 0; mt < 4; ++mt)
#pragma unroll
      for (int nt2 = 0; nt2 < 4; ++nt2)
        acc[mt][nt2] = mfma16(af[mt], bfr[nt2], acc[mt][nt2]);
  }
  const int r4 = (l >> 4) * 4, cc = l & 15;
#pragma unroll
  for (int mt = 0; mt < 4; ++mt)
#pragma unroll
    for (int nt2 = 0; nt2 < 4; ++nt2)
#pragma unroll
      for (int i = 0; i < 4; ++i) {
        int mm = by * 128 + wm + mt * 16 + r4 + i;
        int nn = bx * 128 + wn + nt2 * 16 + cc;
        float v = acc[mt][nt2][i];
        if (bias) v += bias[nn];
        if (act) v = tanhf(v);
        size_t off = (size_t)mm * N + nn;
        if (Cf)  Cf[off]  = v;
        if (Cbf) Cbf[off] = (bf16)v;
      }
}

// ---------------- persistent LSTM chain v6: NaN-sentinel data-poll exchange ----------------
// 64 blocks x 512 threads. Block = (bg: batch-half of 32 rows) x (cg: d-slice of 16
// => 64 gate cols). Waves w = n2 + 2*kq; kq 0,1 = h-half, kq 2,3 = parent half
// (register-prefetched from Hbf one step ahead). NO flags, NO global barrier:
// producers store h(t) into rotating slab Hx[t&3][bg][cg][batch][dim] (pre-filled
// with bf16-NaN 0x7FC0); consumers load MFMA A-frags DIRECTLY from the slab (1KB
// contiguous per instruction) and retry while any u32 == sentinel. Slab parity p is
// re-sentineled at step p+2 (safe: block at t has consumed t-1 => all blocks
// consumed t-2) and rewritten at p+4. Per-step vmcnt(0) after pointwise stores
// orders clear<rewrite and guarantees Hbf(t-1) completeness before slab(t) is
// visible (parent prefetch safety). ONE __syncthreads per step. gls pitch 72
// (conflict-free both sides).
#define LSTM_LDS 73728

__global__ __launch_bounds__(512, 1) void k_lstm_all(
    const bf16* __restrict__ gpre, const bf16* __restrict__ W2bt,
    const int* __restrict__ parent_idx, const bf16* __restrict__ h0bf,
    const float* __restrict__ c0,
    bf16* __restrict__ Hbf,      // batch-major [B*T][512] (parents + downstream)
    bf16* __restrict__ Hx,       // sentinel slabs [4][2][32 cg][32 batch][16] bf16
    float* __restrict__ H) {
  extern __shared__ char smem[];
  float* gls = (float*)smem;     // [2 parity][4 quarters][32 rows][72]

  const int tid = threadIdx.x;
  const int bid = blockIdx.x;
  const int bg = (bid >> 2) & 1;
  const int cg = (bid & 3) | ((bid >> 3) << 2);
  const int d0 = cg * 16;
  const int w = tid >> 6, l = tid & 63;
  const int la32 = l & 31, lhi = l >> 5, kq8 = lhi * 8;
  const int n2 = w & 1, kq = w >> 1;           // kq = K-quarter 0..3
  const int lc = n2 * 32 + la32;               // local gate col 0..63
  const int ng = (lc >> 4) * 512 + d0 + (lc & 15);  // global gate row in W2bt
  const int row = bg * 32 + la32;              // batch row (MFMA A row)

  // ---- weights: 16 K-chunks of this lane's (gate-col, K-quarter), in VGPRs ----
  bf16x8 wf[16];
#pragma unroll
  for (int kc = 0; kc < 16; ++kc)
    wf[kc] = *(const bf16x8*)(W2bt + (size_t)ng * 1024 + kq * 256 + kc * 16 + kq8);

  // ---- pointwise mapping (tid < 256): cells (bg*32+pb, d0+pdh .. +1) ----
  const int pb = (tid & 255) >> 3, pdh = (tid & 7) * 2;
  const int gb = bg * 32 + pb;
  float creg0 = 0.f, creg1 = 0.f;
  unsigned g_pf[4];
  if (tid < 256) {
    creg0 = c0[(size_t)gb * ND + d0 + pdh];
    creg1 = c0[(size_t)gb * ND + d0 + pdh + 1];
#pragma unroll
    for (int g = 0; g < 4; ++g)
      g_pf[g] = *(const unsigned*)(gpre + ((size_t)gb * NT) * 2048 + g * 512 + d0 + pdh);
  }

  // ---- parent A-frags (registers) ----
  union frag { u64 q[2]; bf16x8 v; };
  frag af[16];
#pragma unroll
  for (int kc = 0; kc < 16; ++kc) { af[kc].q[0] = 0ull; af[kc].q[1] = 0ull; }
  bool latereg = false;

  f32x16 acc;
#pragma unroll
  for (int i = 0; i < 16; ++i) acc[i] = 0.f;

  for (int t = 0; t < NT; ++t) {
    float* gp = gls + (t & 1) * 9216;

    if (w < 4) {
      // ---- h-half: sentinel-poll A-frags straight from slab (t-1) ----
      frag hf[16];
      if (t == 0) {
        const bf16* hp = h0bf + (size_t)row * ND + kq * 256 + kq8;
#pragma unroll
        for (int kc = 0; kc < 16; ++kc) {
          hf[kc].q[0] = *(const u64*)(hp + kc * 16);
          hf[kc].q[1] = *(const u64*)(hp + kc * 16 + 4);
        }
      } else {
        // slab frag kc lives at producer cg' = kq*16+kc; 1KB contiguous per load
        const bf16* sb = Hx + ((((t - 1) & 3) * 2 + bg) * 16384)
                            + (size_t)kq * 16 * 512 + la32 * 16 + kq8;
        while (true) {
#pragma unroll
          for (int kc = 0; kc < 16; ++kc) {
            hf[kc].q[0] = __hip_atomic_load((const u64*)(sb + kc * 512),
                                            __ATOMIC_RELAXED, __HIP_MEMORY_SCOPE_AGENT);
            hf[kc].q[1] = __hip_atomic_load((const u64*)(sb + kc * 512 + 4),
                                            __ATOMIC_RELAXED, __HIP_MEMORY_SCOPE_AGENT);
          }
          bool b = false;
#pragma unroll
          for (int kc = 0; kc < 16; ++kc)
            b = b || badq(hf[kc].q[0]) || badq(hf[kc].q[1]);
          if (!__any((int)b)) break;
          __builtin_amdgcn_s_sleep(1);
        }
      }
#pragma unroll
      for (int kc = 0; kc < 16; ++kc) acc = mfma32(hf[kc].v, wf[kc], acc);
    } else {
      // ---- parent half: prefetched; late lanes (pv==t-1) poll slab now ----
      if (__any((int)latereg)) {
        const bf16* sb = Hx + ((((t - 1) & 3) * 2 + bg) * 16384)
                            + (size_t)(kq - 2) * 16 * 512 + la32 * 16 + kq8;
        while (true) {
          bool b = false;
          if (latereg) {
#pragma unroll
            for (int kc = 0; kc < 16; ++kc) {
              af[kc].q[0] = __hip_atomic_load((const u64*)(sb + kc * 512),
                                              __ATOMIC_RELAXED, __HIP_MEMORY_SCOPE_AGENT);
              af[kc].q[1] = __hip_atomic_load((const u64*)(sb + kc * 512 + 4),
                                              __ATOMIC_RELAXED, __HIP_MEMORY_SCOPE_AGENT);
            }
#pragma unroll
            for (int kc = 0; kc < 16; ++kc)
              b = b || badq(af[kc].q[0]) || badq(af[kc].q[1]);
          }
          if (!__any((int)b)) break;
          __builtin_amdgcn_s_sleep(1);
        }
      }
#pragma unroll
      for (int kc = 0; kc < 16; ++kc) acc = mfma32(af[kc].v, wf[kc], acc);
    }

    // ---- K-quarter partials -> gls (parity buffer, pitch 72) ----
#pragma unroll
    for (int i = 0; i < 16; ++i) {
      int r = (i & 3) + 8 * (i >> 2) + 4 * lhi;   // verified 32x32 C/D mapping
      gp[(kq * 32 + r) * 72 + lc] = acc[i];
    }
#pragma unroll
    for (int i = 0; i < 16; ++i) acc[i] = 0.f;
    __syncthreads();  // S_a (only barrier per step)

    if (tid < 256) {
      // ---- pointwise: sum 4 quarters + gpre, gates, cell update ----
      union { unsigned u; bf16 h[2]; } gv[4];
#pragma unroll
      for (int g = 0; g < 4; ++g) gv[g].u = g_pf[g];
      float hn[2];
#pragma unroll
      for (int j = 0; j < 2; ++j) {
        float s[4];
#pragma unroll
        for (int g = 0; g < 4; ++g) {
          float v = 0.f;
#pragma unroll
          for (int q = 0; q < 4; ++q) v += gp[(q * 32 + pb) * 72 + g * 16 + pdh + j];
          s[g] = v + (float)gv[g].h[j];
        }
        float si = 1.f / (1.f + __expf(-s[0]));
        float sf = 1.f / (1.f + __expf(-s[1]));
        float so = 1.f / (1.f + __expf(-s[3]));
        float e2 = __expf(2.f * fminf(fmaxf(s[2], -15.f), 15.f));
        float tg = (e2 - 1.f) / (e2 + 1.f);
        float cp = j ? creg1 : creg0;
        float cn = sf * cp + si * tg;
        float e2c = __expf(2.f * fminf(fmaxf(cn, -15.f), 15.f));
        float tc = (e2c - 1.f) / (e2c + 1.f);
        if (j) creg1 = cn; else creg0 = cn;
        hn[j] = so * tc;
      }
      union { unsigned u; bf16 h[2]; } pk;
      pk.h[0] = (bf16)hn[0]; pk.h[1] = (bf16)hn[1];
      size_t hb = ((size_t)gb * NT + t) * ND + d0 + pdh;
      // batch-major for parents + downstream
      __hip_atomic_store((unsigned*)(Hbf + hb), pk.u, __ATOMIC_RELAXED, __HIP_MEMORY_SCOPE_AGENT);
      // exchange slab (consumers poll this)
      unsigned* sdst = (unsigned*)(Hx + (((t & 3) * 2 + bg) * 16384) + cg * 512 + pb * 16 + pdh);
      __hip_atomic_store(sdst, pk.u, __ATOMIC_RELAXED, __HIP_MEMORY_SCOPE_AGENT);
      // re-sentinel parity (t-2): all blocks have consumed it
      if (t >= 2) {
        unsigned* cdst = (unsigned*)(Hx + ((((t - 2) & 3) * 2 + bg) * 16384) + cg * 512 + pb * 16 + pdh);
        __hip_atomic_store(cdst, SENT, __ATOMIC_RELAXED, __HIP_MEMORY_SCOPE_AGENT);
      }
      *(float2*)(H + hb) = make_float2(hn[0], hn[1]);
      // lag-drain: everything above complete before NEXT step's slab store issues
      asm volatile("s_waitcnt vmcnt(0)" ::: "memory");
      if (t + 1 < NT) {
#pragma unroll
        for (int g = 0; g < 4; ++g)
          g_pf[g] = *(const unsigned*)(gpre + ((size_t)gb * NT + (t + 1)) * 2048 + g * 512 + d0 + pdh);
      }
    } else if (t + 1 < NT) {
      // ---- parent prefetch (waves 4-7): A-frags for step t+1 into registers ----
      int pv = parent_idx[(size_t)row * NT + (t + 1)];
      latereg = (pv == t);
      if (pv < t) {                      // visible history (Hbf complete by lag-drain)
        const bf16* psrc = Hbf + ((size_t)row * NT + pv) * ND + (kq - 2) * 256;
#pragma unroll
        for (int kc = 0; kc < 16; ++kc) {
          af[kc].q[0] = __hip_atomic_load((const u64*)(psrc + kc * 16 + kq8),
                                          __ATOMIC_RELAXED, __HIP_MEMORY_SCOPE_AGENT);
          af[kc].q[1] = __hip_atomic_load((const u64*)(psrc + kc * 16 + kq8 + 4),
                                          __ATOMIC_RELAXED, __HIP_MEMORY_SCOPE_AGENT);
        }
      } else if (!latereg) {             // future parent -> zeros
#pragma unroll
        for (int kc = 0; kc < 16; ++kc) { af[kc].q[0] = 0ull; af[kc].q[1] = 0ull; }
      }
    }
  }
}

// ---------------- fused attention: scores (fp32) + softmax + context ----------------
__global__ __launch_bounds__(256) void k_attn(
    const float* __restrict__ Q, const float* __restrict__ ctx, bf16* __restrict__ Cbf,
    float* __restrict__ prob0, float* __restrict__ prob1) {
  __shared__ float Sl[64 * 257];
  __shared__ float T1[16 * 68];
  __shared__ float T2[16 * 68];
  const int tid = threadIdx.x;
  const int b = blockIdx.x >> 2, ch = blockIdx.x & 3;
  const int t0 = ch * 64;
  const int row0 = b * NT + t0;
  const int ty = tid >> 4, tx = tid & 15;
  const int sl_r = tid >> 2, sl_k = (tid & 3) * 4;

  for (int sc = 0; sc < 4; ++sc) {
    float acc[4][4] = {};
    for (int kc = 0; kc < 512; kc += 16) {
      __syncthreads();
      float4 q4 = *(const float4*)(Q + (size_t)(row0 + sl_r) * ND + kc + sl_k);
      T1[(sl_k + 0) * 68 + sl_r] = q4.x; T1[(sl_k + 1) * 68 + sl_r] = q4.y;
      T1[(sl_k + 2) * 68 + sl_r] = q4.z; T1[(sl_k + 3) * 68 + sl_r] = q4.w;
      float4 c4 = *(const float4*)(ctx + (size_t)(b * NS + sc * 64 + sl_r) * ND + kc + sl_k);
      T2[(sl_k + 0) * 68 + sl_r] = c4.x; T2[(sl_k + 1) * 68 + sl_r] = c4.y;
      T2[(sl_k + 2) * 68 + sl_r] = c4.z; T2[(sl_k + 3) * 68 + sl_r] = c4.w;
      __syncthreads();
#pragma unroll
      for (int kk = 0; kk < 16; ++kk) {
        float4 qv = *(const float4*)(&T1[kk * 68 + ty * 4]);
        float4 cv = *(const float4*)(&T2[kk * 68 + tx * 4]);
        float qa[4] = {qv.x, qv.y, qv.z, qv.w};
        float ca[4] = {cv.x, cv.y, cv.z, cv.w};
#pragma unroll
        for (int i = 0; i < 4; ++i)
#pragma unroll
          for (int j = 0; j < 4; ++j) acc[i][j] += qa[i] * ca[j];
      }
    }
#pragma unroll
    for (int i = 0; i < 4; ++i)
#pragma unroll
      for (int j = 0; j < 4; ++j)
        Sl[(ty * 4 + i) * 257 + sc * 64 + tx * 4 + j] = acc[i][j];
  }
  __syncthreads();

  if (tid < 64) {
    float* row = &Sl[tid * 257];
    float mx = -1e30f;
    for (int s = 0; s < 256; ++s) mx = fmaxf(mx, row[s]);
    float sum = 0.f;
    for (int s = 0; s < 256; ++s) { float e = __expf(row[s] - mx); row[s] = e; sum += e; }
    float inv = 1.f / sum;
    for (int s = 0; s < 256; ++s) row[s] *= inv;
  }
  __syncthreads();
  if (prob0) {
    int pr = tid >> 2, pq = (tid & 3) * 64;
    size_t po = (size_t)(row0 + pr) * NS + pq;
    for (int s = 0; s < 64; s += 4) {
      float4 o; o.x = Sl[pr * 257 + pq + s];     o.y = Sl[pr * 257 + pq + s + 1];
      o.z = Sl[pr * 257 + pq + s + 2];           o.w = Sl[pr * 257 + pq + s + 3];
      *(float4*)(prob0 + po + s) = o;
      *(float4*)(prob1 + po + s) = o;
    }
  }

  const int c_sr = tid >> 4, c_n4 = (tid & 15) * 4;
  for (int dc = 0; dc < 512; dc += 64) {
    float acc[4][4] = {};
    for (int s0c = 0; s0c < 256; s0c += 16) {
      __syncthreads();
      *(float4*)(&T2[c_sr * 68 + c_n4]) =
          *(const float4*)(ctx + (size_t)(b * NS + s0c + c_sr) * ND + dc + c_n4);
      __syncthreads();
#pragma unroll
      for (int kk = 0; kk < 16; ++kk) {
        float p0 = Sl[(ty * 4 + 0) * 257 + s0c + kk];
        float p1 = Sl[(ty * 4 + 1) * 257 + s0c + kk];
        float p2 = Sl[(ty * 4 + 2) * 257 + s0c + kk];
        float p3 = Sl[(ty * 4 + 3) * 257 + s0c + kk];
        float4 cv = *(const float4*)(&T2[kk * 68 + tx * 4]);
        float ca[4] = {cv.x, cv.y, cv.z, cv.w};
#pragma unroll
        for (int j = 0; j < 4; ++j) {
          acc[0][j] += p0 * ca[j]; acc[1][j] += p1 * ca[j];
          acc[2][j] += p2 * ca[j]; acc[3][j] += p3 * ca[j];
        }
      }
    }
#pragma unroll
    for (int i = 0; i < 4; ++i)
#pragma unroll
      for (int j = 0; j < 4; ++j)
        Cbf[(size_t)(row0 + ty * 4 + i) * ND + dc + tx * 4 + j] = (bf16)acc[i][j];
  }
}

// ---------------- host ----------------
extern "C" void kernel_launch(void* const* d_in, const int* in_sizes, int n_in,
                              void* d_out, int out_size, void* d_ws, size_t ws_size,
                              hipStream_t stream) {
  const int*   nt       = (const int*)d_in[0];
  const int*   prules   = (const int*)d_in[1];
  const int*   parules  = (const int*)d_in[2];
  const int*   pidx     = (const int*)d_in[3];
  const float* src_ctx  = (const float*)d_in[4];
  const float* rest_ctx = (const float*)d_in[5];
  const float* h0       = (const float*)d_in[8];
  const float* c0       = (const float*)d_in[9];
  const float* nt_emb   = (const float*)d_in[10];
  const float* rule_emb = (const float*)d_in[11];
  const float* Wih      = (const float*)d_in[12];
  const float* Whh      = (const float*)d_in[13];
  const float* b_lstm   = (const float*)d_in[14];
  const float* Wa_src   = (const float*)d_in[15];
  const float* Wo_src   = (const float*)d_in[16];
  const float* Wa_var   = (const float*)d_in[17];
  const float* Wo_var   = (const float*)d_in[18];
  const float* Wl       = (const float*)d_in[19];
  const float* bl       = (const float*)d_in[20];
  float* out = (float*)d_out;

  char* p = (char*)d_ws;
  bf16*  Abuf    = (bf16*)p;  p += 50331648;   // [16384][1536]
  bf16*  gpre    = (bf16*)p;  p += 67108864;   // [16384][2048]
  float* H       = (float*)p; p += 33554432;   // [16384][512]
  bf16*  Hbf     = (bf16*)p;  p += 16777216;
  float* SRCOUT  = (float*)p; p += 33554432;
  bf16*  SRCOUTb = (bf16*)p;  p += 16777216;
  bf16*  Wemb_bt = (bf16*)p;  p += 6291456;    // [2048][1536]
  bf16*  W2bt    = (bf16*)p;  p += 4194304;    // [2048][1024] = [Whh | Wih_par]
  bf16*  Wos_bt  = (bf16*)p;  p += 1048576;
  bf16*  Wov_bt  = (bf16*)p;  p += 1048576;
  bf16*  Wl_bt   = (bf16*)p;  p += 1572864;
  bf16*  h0bf    = (bf16*)p;  p += 65536;
  bf16*  Hx      = (bf16*)p;  p += 262144;     // [4][2][32][32][16] sentinel slabs
  float* Q1    = (float*)Abuf;
  bf16*  C1bf  = (bf16*)((char*)Abuf + 33554432);
  float* Q2    = (float*)gpre;
  bf16*  C2bf  = (bf16*)((char*)gpre + 33554432);
  bf16*  VARbf = (bf16*)((char*)gpre + 50331648);
  // split-bf16 projection temporaries (aliases of dead regions):
  bf16*  Hlo   = (bf16*)((char*)gpre + 16777216);  // dead before Q2 write
  bf16*  SOlo  = (bf16*)Abuf;                      // Q1 dead after src-attn
  bf16*  Was3  = Wemb_bt;                          // [512][1536] = [Whi|Wlo|Whi]
  bf16*  Wav3  = Wemb_bt + 786432;                 // (Wemb_bt dead after gpre GEMM)
  float* out_p0 = out + 8388608;
  float* out_p1 = out + 12582912;

  hipFuncSetAttribute(reinterpret_cast<const void*>(k_lstm_all),
                      hipFuncAttributeMaxDynamicSharedMemorySize, LSTM_LDS);

  k_cast_bt<<<(2048*1536+255)/256, 256, 0, stream>>>(Wemb_bt, 1536, 2048, 1536, Wih, 2048, 0, 0, 0);
  k_cast_bt<<<(2048*512 +255)/256, 256, 0, stream>>>(W2bt,        1024, 2048, 512, Whh, 512, 0, 0, 0);
  k_cast_bt<<<(2048*512 +255)/256, 256, 0, stream>>>(W2bt + 512,  1024, 2048, 512, Wih, 2048, 1536, 0, 0);
  k_cast_bt<<<(512*1024 +255)/256, 256, 0, stream>>>(Wos_bt, 1024, 512, 1024, Wo_src, 512, 0, 1, 0);
  k_cast_bt<<<(512*1024 +255)/256, 256, 0, stream>>>(Wov_bt, 1024, 512, 1024, Wo_var, 512, 0, 1, 0);
  k_cast_bt<<<(512*1536 +255)/256, 256, 0, stream>>>(Wl_bt,  1536, 512, 1536, Wl, 512, 0, 1, 0);
  k_init<<<128, 256, 0, stream>>>(h0, h0bf, (unsigned*)Hx);
  k_embed<<<16384, 128, 0, stream>>>(nt, prules, parules, nt_emb, rule_emb, Abuf);

  k_gemm<<<2048, 256, 0, stream>>>(Abuf, 1536, nullptr, 0, nullptr, 0,
                                   Wemb_bt, 1536, 2048, 16, b_lstm, 0, nullptr, gpre);

  // Wemb_bt now dead -> build split-bf16 Wa panels into it
  k_cast_bt<<<(512*512+255)/256, 256, 0, stream>>>(Was3 + 0,    1536, 512, 512, Wa_src, 512, 0, 1, 0);
  k_cast_bt<<<(512*512+255)/256, 256, 0, stream>>>(Was3 + 512,  1536, 512, 512, Wa_src, 512, 0, 1, 1);
  k_cast_bt<<<(512*512+255)/256, 256, 0, stream>>>(Was3 + 1024, 1536, 512, 512, Wa_src, 512, 0, 1, 0);
  k_cast_bt<<<(512*512+255)/256, 256, 0, stream>>>(Wav3 + 0,    1536, 512, 512, Wa_var, 512, 0, 1, 0);
  k_cast_bt<<<(512*512+255)/256, 256, 0, stream>>>(Wav3 + 512,  1536, 512, 512, Wa_var, 512, 0, 1, 1);
  k_cast_bt<<<(512*512+255)/256, 256, 0, stream>>>(Wav3 + 1024, 1536, 512, 512, Wa_var, 512, 0, 1, 0);

  k_lstm_all<<<64, 512, LSTM_LDS, stream>>>(gpre, W2bt, pidx, h0bf, c0, Hbf, Hx, H);

  // Q1 = H @ Wa_src in split-bf16: Hbf@Whi + Hbf@Wlo + Hlo@Whi  (fp32-accurate)
  k_lo<<<16384*512/4/256, 256, 0, stream>>>(H, Hbf, Hlo, 16384*512/4);
  k_gemm<<<512, 256, 0, stream>>>(Hbf, 512, Hbf, 512, Hlo, 512,
                                  Was3, 1536, 512, 4, nullptr, 0, Q1, nullptr);
  k_attn<<<256, 256, 0, stream>>>(Q1, src_ctx, C1bf, nullptr, nullptr);
  k_gemm<<<512, 256, 0, stream>>>(C1bf, 512, Hbf, 512, nullptr, 0,
                                  Wos_bt, 1024, 512, 4, nullptr, 1, SRCOUT, SRCOUTb);
  // Q2 = SRCOUT @ Wa_var in split-bf16
  k_lo<<<16384*512/4/256, 256, 0, stream>>>(SRCOUT, SRCOUTb, SOlo, 16384*512/4);
  k_gemm<<<512, 256, 0, stream>>>(SRCOUTb, 512, SRCOUTb, 512, SOlo, 512,
                                  Wav3, 1536, 512, 4, nullptr, 0, Q2, nullptr);
  k_attn<<<256, 256, 0, stream>>>(Q2, rest_ctx, C2bf, out_p0, out_p1);
  k_gemm<<<512, 256, 0, stream>>>(C2bf, 512, SRCOUTb, 512, nullptr, 0,
                                  Wov_bt, 1024, 512, 4, nullptr, 1, nullptr, VARbf);
  k_gemm<<<512, 256, 0, stream>>>(Hbf, 512, SRCOUTb, 512, VARbf, 512,
                                  Wl_bt, 1536, 512, 4, bl, 1, out, nullptr);
}